// Round 9
// baseline (118.341 us; speedup 1.0000x reference)
//
#include <hip/hip_runtime.h>

#define EPV    0.0001f
#define EPMAXV 30.0f
#define RTOLV  1e-5f
#define ATOLV  1e-8f
#define NPART  1024   // k_main grid size (4 blocks/CU co-resident)
#define CHUNK  112    // points per LDS chunk: ceil(3072/112)=28 -> 36*28=1008 chunks <= 1024

// Force a value to stay resident in a VGPR (defeats rematerialization/reload).
#define PIN(x) asm volatile("" : "+v"(x))

// ---------------------------------------------------------------------------
// ws layout: count(4B) | done(4B) | pad | rowcnt[L] | partials[NPART] |
//            pF[L*12] | tF[L*12] | rec[(L+cap)*24]
// rec record (24 floats): [0..8] P=R_P rows, [9..17] N=-R_T rows,
//                         [18..20] k = -(P*Op + N*Ot), [21..23] pad
// k_main per cell: u = P*c + N*t + k;  r = min(sqrt(|u|^2+3eps), 30)
// Pair slot order within a row is arbitrary (mean over frames is order-free);
// pred+target for one (i,j) share a slot, which is all correctness needs.
// ---------------------------------------------------------------------------

__device__ inline void write_rec(float* __restrict__ rec,
                                 const float Rp[9], const float Op[3],
                                 const float Rt[9], const float Ot[3]) {
    float P[9], N[9];
#pragma unroll
    for (int k = 0; k < 9; k++) { P[k] = Rp[k]; N[k] = -Rt[k]; }
    float kx = -(P[0] * Op[0] + P[1] * Op[1] + P[2] * Op[2]
               + N[0] * Ot[0] + N[1] * Ot[1] + N[2] * Ot[2]);
    float ky = -(P[3] * Op[0] + P[4] * Op[1] + P[5] * Op[2]
               + N[3] * Ot[0] + N[4] * Ot[1] + N[5] * Ot[2]);
    float kz = -(P[6] * Op[0] + P[7] * Op[1] + P[8] * Op[2]
               + N[6] * Ot[0] + N[7] * Ot[1] + N[8] * Ot[2]);
    float4* r4 = (float4*)rec;   // rec is 16B-aligned (record = 96 B)
    r4[0] = make_float4(P[0], P[1], P[2], P[3]);
    r4[1] = make_float4(P[4], P[5], P[6], P[7]);
    r4[2] = make_float4(P[8], N[0], N[1], N[2]);
    r4[3] = make_float4(N[3], N[4], N[5], N[6]);
    r4[4] = make_float4(N[7], N[8], kx, ky);
    r4[5] = make_float4(kz, 0.f, 0.f, 0.f);
}

// Fused: blocks [0, nrb) wave-per-row popcount (int4 scan);
// blocks [nrb, nrb+nbase) build base frames + base records.
// Block 0 thread 0 also zeroes the k_main completion counter.
__global__ void k_prep(const int* __restrict__ m, int L, unsigned int* __restrict__ rowcnt,
                       const float* __restrict__ rot, const float* __restrict__ trans,
                       const float* __restrict__ target, int nrb,
                       float* __restrict__ pF, float* __restrict__ tF,
                       float* __restrict__ rec, unsigned int* __restrict__ done) {
    if (blockIdx.x == 0 && threadIdx.x == 0) *done = 0u;
    if ((int)blockIdx.x < nrb) {
        int i = blockIdx.x * 4 + (threadIdx.x >> 6);
        if (i >= L) return;
        int lane = threadIdx.x & 63;
        const int4* row4 = (const int4*)(m + (size_t)i * L);
        unsigned int c = 0;
        for (int b = lane; b * 4 < L; b += 64) {
            int4 v = row4[b];
            int j = b * 4;
            c += (unsigned)((j + 0 > i) & (v.x == 1)) + (unsigned)((j + 1 > i) & (v.y == 1))
               + (unsigned)((j + 2 > i) & (v.z == 1)) + (unsigned)((j + 3 > i) & (v.w == 1));
        }
#pragma unroll
        for (int off = 1; off < 64; off <<= 1) c += __shfl_xor(c, off, 64);
        if (lane == 0) rowcnt[i] = c;
        return;
    }
    int l = ((int)blockIdx.x - nrb) * 256 + threadIdx.x;
    if (l >= L) return;
    float Rp[9], Op[3];
#pragma unroll
    for (int k = 0; k < 9; k++) Rp[k] = rot[l * 9 + k];
#pragma unroll
    for (int k = 0; k < 3; k++) Op[k] = trans[l * 3 + k];
    float* pf = pF + l * 12;
#pragma unroll
    for (int k = 0; k < 9; k++) pf[k] = Rp[k];
#pragma unroll
    for (int k = 0; k < 3; k++) pf[9 + k] = Op[k];
    // rigid_from_3(target[l])
    const float* tg = target + l * 9;
    float x1x = tg[0], x1y = tg[1], x1z = tg[2];
    float x2x = tg[3], x2y = tg[4], x2z = tg[5];
    float x3x = tg[6], x3y = tg[7], x3z = tg[8];
    float v1x = x3x - x2x, v1y = x3y - x2y, v1z = x3z - x2z;
    float v2x = x1x - x2x, v2y = x1y - x2y, v2z = x1z - x2z;
    float n1 = sqrtf(v1x * v1x + v1y * v1y + v1z * v1z) + 0.001f;
    float e1x = v1x / n1, e1y = v1y / n1, e1z = v1z / n1;
    float c = e1x * v2x + e1y * v2y + e1z * v2z;
    float u2x = v2x - c * e1x, u2y = v2y - c * e1y, u2z = v2z - c * e1z;
    float n2 = sqrtf(u2x * u2x + u2y * u2y + u2z * u2z) + 1e-8f;
    float e2x = u2x / n2, e2y = u2y / n2, e2z = u2z / n2;
    float Rt[9], Ot[3];
    Rt[0] = e1x; Rt[1] = e1y; Rt[2] = e1z;
    Rt[3] = e2x; Rt[4] = e2y; Rt[5] = e2z;
    Rt[6] = e1y * e2z - e1z * e2y;
    Rt[7] = e1z * e2x - e1x * e2z;
    Rt[8] = e1x * e2y - e1y * e2x;
    Ot[0] = x2x; Ot[1] = x2y; Ot[2] = x2z;
    float* tf = tF + l * 12;
#pragma unroll
    for (int k = 0; k < 9; k++) tf[k] = Rt[k];
#pragma unroll
    for (int k = 0; k < 3; k++) tf[9 + k] = Ot[k];
    write_rec(rec + (size_t)l * 24, Rp, Op, Rt, Ot);
}

// 12-float frame records A,B -> merged R[9],O[3] (registers)
__device__ inline void merge_frames(const float* __restrict__ A, const float* __restrict__ B,
                                    float R[9], float O[3]) {
    const float* RA = A; const float* OA = A + 9;
    const float* RB = B; const float* OB = B + 9;
    bool close = (fabsf(OA[0] - OB[0]) <= ATOLV + RTOLV * fabsf(OB[0])) &&
                 (fabsf(OA[1] - OB[1]) <= ATOLV + RTOLV * fabsf(OB[1])) &&
                 (fabsf(OA[2] - OB[2]) <= ATOLV + RTOLV * fabsf(OB[2]));
    float d0 = OB[0] - OA[0], d1 = OB[1] - OA[1], d2 = OB[2] - OA[2];
    float nd = sqrtf(d0 * d0 + d1 * d1 + d2 * d2);
    float nds = (nd == 0.f) ? 1.f : nd;
    float X0 = d0 / nds, X1 = d1 / nds, X2 = d2 / nds;
    float Za0 = RA[6] + RB[6], Za1 = RA[7] + RB[7], Za2 = RA[8] + RB[8];
    float Zs0 = RA[6] - RB[6], Zs1 = RA[7] - RB[7], Zs2 = RA[8] - RB[8];
    float na = sqrtf(Za0 * Za0 + Za1 * Za1 + Za2 * Za2);
    float ns = sqrtf(Zs0 * Zs0 + Zs1 * Zs1 + Zs2 * Zs2);
    float nas = (na == 0.f) ? 1.f : na;
    float nss = (ns == 0.f) ? 1.f : ns;
    float Z0, Z1, Z2;
    if (na > ns) { Z0 = Za0 / nas; Z1 = Za1 / nas; Z2 = Za2 / nas; }
    else         { Z0 = Zs0 / nss; Z1 = Zs1 / nss; Z2 = Zs2 / nss; }
    float Y0 = Z1 * X2 - Z2 * X1;
    float Y1 = Z2 * X0 - Z0 * X2;
    float Y2 = Z0 * X1 - Z1 * X0;
    bool nanbad = (Y0 != Y0) || (Y1 != Y1) || (Y2 != Y2);
    float C0 = X1 * Y2 - X2 * Y1;
    float C1 = X2 * Y0 - X0 * Y2;
    float C2 = X0 * Y1 - X1 * Y0;
    float dotv = C0 * Z0 + C1 * Z1 + C2 * Z2;
    if (dotv < 0.f) { Y0 = -Y0; Y1 = -Y1; Y2 = -Y2; }
    bool bad = close || (nd == 0.f) || (na == 0.f) || (ns == 0.f) || nanbad;
    if (bad) {
#pragma unroll
        for (int k = 0; k < 9; k++) R[k] = RA[k];
#pragma unroll
        for (int k = 0; k < 3; k++) O[k] = OA[k];
    } else {
        R[0] = X0; R[1] = X1; R[2] = X2;
        R[3] = Y0; R[4] = Y1; R[5] = Y2;
        R[6] = Z0; R[7] = Z1; R[8] = Z2;
        O[0] = 0.5f * (OA[0] + OB[0]);
        O[1] = 0.5f * (OA[1] + OB[1]);
        O[2] = 0.5f * (OA[2] + OB[2]);
    }
}

// Fused fill+merge: wave-per-row, int4 scan (4 cols/lane). Slot order within a
// row is lane-major (arbitrary but bijective -> correct, see header comment).
// Exclusive row prefix recomputed from rowcnt (L2-resident).
__global__ void k_fillmerge(const int* __restrict__ m, int L,
                            const unsigned int* __restrict__ rowcnt,
                            unsigned int* __restrict__ count, int cap,
                            const float* __restrict__ pF, const float* __restrict__ tF,
                            float* __restrict__ rec) {
    int i = blockIdx.x * 4 + (threadIdx.x >> 6);
    int lane = threadIdx.x & 63;

    if (blockIdx.x == 0 && (threadIdx.x >> 6) == 0) {
        unsigned int t = 0;
        for (int r = lane; r < L; r += 64) t += rowcnt[r];
#pragma unroll
        for (int off = 1; off < 64; off <<= 1) t += __shfl_xor(t, off, 64);
        if (lane == 0) *count = t;
    }
    if (i >= L) return;

    unsigned int p = 0;
    for (int r = lane; r < i; r += 64) p += rowcnt[r];
#pragma unroll
    for (int off = 1; off < 64; off <<= 1) p += __shfl_xor(p, off, 64);
    unsigned int base = p;

    const int4* row4 = (const int4*)(m + (size_t)i * L);
    for (int b = lane; b * 4 < L; b += 64) {
        int4 v = row4[b];
        int j = b * 4;
        unsigned h0 = (unsigned)((j + 0 > i) & (v.x == 1));
        unsigned h1 = (unsigned)((j + 1 > i) & (v.y == 1));
        unsigned h2 = (unsigned)((j + 2 > i) & (v.z == 1));
        unsigned h3 = (unsigned)((j + 3 > i) & (v.w == 1));
        unsigned hc = h0 + h1 + h2 + h3;
        // inclusive lane scan of hc
        unsigned inc = hc;
#pragma unroll
        for (int off = 1; off < 64; off <<= 1) {
            unsigned t = __shfl_up(inc, off, 64);
            if (lane >= off) inc += t;
        }
        unsigned slot = base + (inc - hc);
        if (hc) {
#pragma unroll
            for (int k = 0; k < 4; k++) {
                unsigned hk = (k == 0) ? h0 : (k == 1) ? h1 : (k == 2) ? h2 : h3;
                if (hk) {
                    int jj = j + k;
                    if (slot < (unsigned int)cap) {
                        float Rp[9], Op[3], Rt[9], Ot[3];
                        merge_frames(pF + i * 12, pF + jj * 12, Rp, Op);
                        merge_frames(tF + i * 12, tF + jj * 12, Rt, Ot);
                        write_rec(rec + (size_t)(L + slot) * 24, Rp, Op, Rt, Ot);
                    }
                    slot++;
                }
            }
        }
        base += __shfl(inc, 63, 64);   // wave total this chunk
    }
}

// Frame-major: each thread owns ONE frame; its 21 constants are PINNED into
// VGPRs (inline-asm) so the allocator cannot rematerialize/reload them per
// iteration. Points staged in LDS as padded float4 (broadcast, conflict-free).
// Last-finishing block reduces the 1024 partials and writes out (no k_final).
__global__ __launch_bounds__(256, 4)
void k_main(const float* __restrict__ coor, const float* __restrict__ target,
            const float* __restrict__ rec, const unsigned int* __restrict__ count,
            int cap, int L, int Npts, double* __restrict__ partials,
            unsigned int* __restrict__ done, float* __restrict__ out) {
    __shared__ float4 sC[CHUNK];
    __shared__ float4 sT[CHUNK];
    __shared__ float sRed[4];
    __shared__ int sLast;
    __shared__ double sRd[4];
    unsigned int cnt = *count;
    if (cnt > (unsigned int)cap) cnt = (unsigned int)cap;
    int F = L + (int)cnt;
    int nfb = (F + 255) >> 8;
    int nyc = (Npts + CHUNK - 1) / CHUNK;
    int total = nfb * nyc;
    float a0 = 0.f, a1 = 0.f;

    for (int chunk = blockIdx.x; chunk < total; chunk += gridDim.x) {
        int fb = chunk % nfb;
        int yc = chunk / nfb;
        int n0 = yc * CHUNK;
        int npts = Npts - n0; if (npts > CHUNK) npts = CHUNK;
        __syncthreads();   // protect LDS reuse across grid-stride iterations
        for (int idx = threadIdx.x; idx < npts; idx += 256) {
            int g = (n0 + idx) * 3;
            sC[idx] = make_float4(coor[g], coor[g + 1], coor[g + 2], 0.f);
            sT[idx] = make_float4(target[g], target[g + 1], target[g + 2], 0.f);
        }
        __syncthreads();
        int f = fb * 256 + threadIdx.x;
        if (f >= F) continue;   // both barriers above executed by all threads

        const float4* fr = (const float4*)(rec + (size_t)f * 24);
        float4 r0 = fr[0], r1 = fr[1], r2 = fr[2], r3 = fr[3], r4 = fr[4], r5 = fr[5];
        float P00 = r0.x, P01 = r0.y, P02 = r0.z;
        float P10 = r0.w, P11 = r1.x, P12 = r1.y;
        float P20 = r1.z, P21 = r1.w, P22 = r2.x;
        float N00 = r2.y, N01 = r2.z, N02 = r2.w;
        float N10 = r3.x, N11 = r3.y, N12 = r3.z;
        float N20 = r3.w, N21 = r4.x, N22 = r4.y;
        float kx  = r4.z, ky  = r4.w, kz  = r5.x;
        PIN(P00); PIN(P01); PIN(P02); PIN(P10); PIN(P11); PIN(P12);
        PIN(P20); PIN(P21); PIN(P22);
        PIN(N00); PIN(N01); PIN(N02); PIN(N10); PIN(N11); PIN(N12);
        PIN(N20); PIN(N21); PIN(N22);
        PIN(kx);  PIN(ky);  PIN(kz);

#pragma unroll 4
        for (int n = 0; n < npts; n++) {
            float4 c = sC[n];
            float4 t = sT[n];
            float ux = kx + P00 * c.x + P01 * c.y + P02 * c.z
                          + N00 * t.x + N01 * t.y + N02 * t.z;
            float uy = ky + P10 * c.x + P11 * c.y + P12 * c.z
                          + N10 * t.x + N11 * t.y + N12 * t.z;
            float uz = kz + P20 * c.x + P21 * c.y + P22 * c.z
                          + N20 * t.x + N21 * t.y + N22 * t.z;
            float s = ux * ux + uy * uy + uz * uz + 3.0f * EPV;
            float r = fminf(__builtin_amdgcn_sqrtf(s), EPMAXV);
            if (n & 1) a1 += r; else a0 += r;
        }
    }

    float a = a0 + a1;
#pragma unroll
    for (int off = 32; off > 0; off >>= 1) a += __shfl_down(a, off, 64);
    int lane = threadIdx.x & 63, wv = threadIdx.x >> 6;
    if (lane == 0) sRed[wv] = a;
    __syncthreads();
    if (threadIdx.x == 0) {
        partials[blockIdx.x] = (double)(sRed[0] + sRed[1] + sRed[2] + sRed[3]);
        __threadfence();
        unsigned int prev = atomicAdd(done, 1u);
        sLast = (prev == gridDim.x - 1u) ? 1 : 0;
    }
    __syncthreads();
    if (sLast) {
        __threadfence();   // acquire: make all partials visible
        double d = 0.0;
        for (int i = threadIdx.x; i < (int)gridDim.x; i += 256) d += partials[i];
#pragma unroll
        for (int off = 32; off > 0; off >>= 1) d += __shfl_down(d, off, 64);
        if (lane == 0) sRd[wv] = d;
        __syncthreads();
        if (threadIdx.x == 0) {
            double tot = sRd[0] + sRd[1] + sRd[2] + sRd[3];
            out[0] = (float)(tot / ((double)Npts * (double)F));
        }
    }
}

extern "C" void kernel_launch(void* const* d_in, const int* in_sizes, int n_in,
                              void* d_out, int out_size, void* d_ws, size_t ws_size,
                              hipStream_t stream) {
    const float* coor   = (const float*)d_in[0];
    const float* rot    = (const float*)d_in[1];
    const float* trans  = (const float*)d_in[2];
    const float* target = (const float*)d_in[3];
    const int*   matrix = (const int*)d_in[4];
    int L    = in_sizes[2] / 3;     // trans has L*3 elements
    int Npts = 3 * L;

    char* ws = (char*)d_ws;
    size_t off = 16;
    unsigned int* count  = (unsigned int*)ws;
    unsigned int* done   = (unsigned int*)(ws + 4);
    unsigned int* rowcnt = (unsigned int*)(ws + off); off += 4 * (size_t)L;
    off = (off + 15) & ~(size_t)15;
    double* partials = (double*)(ws + off); off += 8 * (size_t)NPART;
    off = (off + 15) & ~(size_t)15;
    float* pF = (float*)(ws + off); off += 48 * (size_t)L;   // L*12 floats
    float* tF = (float*)(ws + off); off += 48 * (size_t)L;
    off = (off + 15) & ~(size_t)15;
    // remaining need(cap) = 96*(L+cap)  (rec records, 96 B each)
    long cap_ws = ((long)ws_size - (long)off - 96L * (long)L) / 96;
    long capl = cap_ws < 32768 ? cap_ws : 32768;
    if (capl < 0) capl = 0;
    int cap = (int)capl;
    float* rec = (float*)(ws + off);

    int nrb   = (L + 3) / 4;       // wave-per-row blocks
    int nbase = (L + 255) / 256;
    k_prep<<<nrb + nbase, 256, 0, stream>>>(matrix, L, rowcnt, rot, trans, target,
                                            nrb, pF, tF, rec, done);
    k_fillmerge<<<nrb, 256, 0, stream>>>(matrix, L, rowcnt, count, cap, pF, tF, rec);
    k_main<<<NPART, 256, 0, stream>>>(coor, target, rec, count, cap, L, Npts,
                                      partials, done, (float*)d_out);
}

// Round 10
// 101.885 us; speedup vs baseline: 1.1615x; 1.1615x over previous
//
#include <hip/hip_runtime.h>

#define EPV    0.0001f
#define EPMAXV 30.0f
#define RTOLV  1e-5f
#define ATOLV  1e-8f
#define NPART  1024   // k_main grid size (4 blocks/CU co-resident)
#define CHUNK  112    // points per LDS chunk: ceil(3072/112)=28 -> 36*28=1008 chunks <= 1024

// Force a value to stay resident in a VGPR (defeats rematerialization/reload).
#define PIN(x) asm volatile("" : "+v"(x))

// ---------------------------------------------------------------------------
// ws layout: count | rowcnt[L] | partials[NPART] | pF[L*12] | tF[L*12] | rec[(L+cap)*24]
// rec record (24 floats): [0..8] P=R_P rows, [9..17] N=-R_T rows,
//                         [18..20] k = -(P*Op + N*Ot), [21..23] pad
// k_main per cell: u = P*c + N*t + k;  r = min(sqrt(|u|^2+3eps), 30)
// NOTE (R9 lesson): no same-address returning atomics anywhere — 1024
// contended atomicAdds at block retirement cost ~15 us (measured R9 vs R8).
// ---------------------------------------------------------------------------

__device__ inline void write_rec(float* __restrict__ rec,
                                 const float Rp[9], const float Op[3],
                                 const float Rt[9], const float Ot[3]) {
    float P[9], N[9];
#pragma unroll
    for (int k = 0; k < 9; k++) { P[k] = Rp[k]; N[k] = -Rt[k]; }
    float kx = -(P[0] * Op[0] + P[1] * Op[1] + P[2] * Op[2]
               + N[0] * Ot[0] + N[1] * Ot[1] + N[2] * Ot[2]);
    float ky = -(P[3] * Op[0] + P[4] * Op[1] + P[5] * Op[2]
               + N[3] * Ot[0] + N[4] * Ot[1] + N[5] * Ot[2]);
    float kz = -(P[6] * Op[0] + P[7] * Op[1] + P[8] * Op[2]
               + N[6] * Ot[0] + N[7] * Ot[1] + N[8] * Ot[2]);
    float4* r4 = (float4*)rec;   // rec is 16B-aligned (record = 96 B)
    r4[0] = make_float4(P[0], P[1], P[2], P[3]);
    r4[1] = make_float4(P[4], P[5], P[6], P[7]);
    r4[2] = make_float4(P[8], N[0], N[1], N[2]);
    r4[3] = make_float4(N[3], N[4], N[5], N[6]);
    r4[4] = make_float4(N[7], N[8], kx, ky);
    r4[5] = make_float4(kz, 0.f, 0.f, 0.f);
}

// Fused: blocks [0, nrb) wave-per-row popcount (int4 scan);
// blocks [nrb, nrb+nbase) build base frames + base records.
__global__ void k_prep(const int* __restrict__ m, int L, unsigned int* __restrict__ rowcnt,
                       const float* __restrict__ rot, const float* __restrict__ trans,
                       const float* __restrict__ target, int nrb,
                       float* __restrict__ pF, float* __restrict__ tF,
                       float* __restrict__ rec) {
    if ((int)blockIdx.x < nrb) {
        int i = blockIdx.x * 4 + (threadIdx.x >> 6);
        if (i >= L) return;
        int lane = threadIdx.x & 63;
        const int4* row4 = (const int4*)(m + (size_t)i * L);
        unsigned int c = 0;
        for (int b = lane; b * 4 < L; b += 64) {
            int4 v = row4[b];
            int j = b * 4;
            c += (unsigned)((j + 0 > i) & (v.x == 1)) + (unsigned)((j + 1 > i) & (v.y == 1))
               + (unsigned)((j + 2 > i) & (v.z == 1)) + (unsigned)((j + 3 > i) & (v.w == 1));
        }
#pragma unroll
        for (int off = 1; off < 64; off <<= 1) c += __shfl_xor(c, off, 64);
        if (lane == 0) rowcnt[i] = c;
        return;
    }
    int l = ((int)blockIdx.x - nrb) * 256 + threadIdx.x;
    if (l >= L) return;
    float Rp[9], Op[3];
#pragma unroll
    for (int k = 0; k < 9; k++) Rp[k] = rot[l * 9 + k];
#pragma unroll
    for (int k = 0; k < 3; k++) Op[k] = trans[l * 3 + k];
    float* pf = pF + l * 12;
#pragma unroll
    for (int k = 0; k < 9; k++) pf[k] = Rp[k];
#pragma unroll
    for (int k = 0; k < 3; k++) pf[9 + k] = Op[k];
    // rigid_from_3(target[l])
    const float* tg = target + l * 9;
    float x1x = tg[0], x1y = tg[1], x1z = tg[2];
    float x2x = tg[3], x2y = tg[4], x2z = tg[5];
    float x3x = tg[6], x3y = tg[7], x3z = tg[8];
    float v1x = x3x - x2x, v1y = x3y - x2y, v1z = x3z - x2z;
    float v2x = x1x - x2x, v2y = x1y - x2y, v2z = x1z - x2z;
    float n1 = sqrtf(v1x * v1x + v1y * v1y + v1z * v1z) + 0.001f;
    float e1x = v1x / n1, e1y = v1y / n1, e1z = v1z / n1;
    float c = e1x * v2x + e1y * v2y + e1z * v2z;
    float u2x = v2x - c * e1x, u2y = v2y - c * e1y, u2z = v2z - c * e1z;
    float n2 = sqrtf(u2x * u2x + u2y * u2y + u2z * u2z) + 1e-8f;
    float e2x = u2x / n2, e2y = u2y / n2, e2z = u2z / n2;
    float Rt[9], Ot[3];
    Rt[0] = e1x; Rt[1] = e1y; Rt[2] = e1z;
    Rt[3] = e2x; Rt[4] = e2y; Rt[5] = e2z;
    Rt[6] = e1y * e2z - e1z * e2y;
    Rt[7] = e1z * e2x - e1x * e2z;
    Rt[8] = e1x * e2y - e1y * e2x;
    Ot[0] = x2x; Ot[1] = x2y; Ot[2] = x2z;
    float* tf = tF + l * 12;
#pragma unroll
    for (int k = 0; k < 9; k++) tf[k] = Rt[k];
#pragma unroll
    for (int k = 0; k < 3; k++) tf[9 + k] = Ot[k];
    write_rec(rec + (size_t)l * 24, Rp, Op, Rt, Ot);
}

// 12-float frame records A,B -> merged R[9],O[3] (registers)
__device__ inline void merge_frames(const float* __restrict__ A, const float* __restrict__ B,
                                    float R[9], float O[3]) {
    const float* RA = A; const float* OA = A + 9;
    const float* RB = B; const float* OB = B + 9;
    bool close = (fabsf(OA[0] - OB[0]) <= ATOLV + RTOLV * fabsf(OB[0])) &&
                 (fabsf(OA[1] - OB[1]) <= ATOLV + RTOLV * fabsf(OB[1])) &&
                 (fabsf(OA[2] - OB[2]) <= ATOLV + RTOLV * fabsf(OB[2]));
    float d0 = OB[0] - OA[0], d1 = OB[1] - OA[1], d2 = OB[2] - OA[2];
    float nd = sqrtf(d0 * d0 + d1 * d1 + d2 * d2);
    float nds = (nd == 0.f) ? 1.f : nd;
    float X0 = d0 / nds, X1 = d1 / nds, X2 = d2 / nds;
    float Za0 = RA[6] + RB[6], Za1 = RA[7] + RB[7], Za2 = RA[8] + RB[8];
    float Zs0 = RA[6] - RB[6], Zs1 = RA[7] - RB[7], Zs2 = RA[8] - RB[8];
    float na = sqrtf(Za0 * Za0 + Za1 * Za1 + Za2 * Za2);
    float ns = sqrtf(Zs0 * Zs0 + Zs1 * Zs1 + Zs2 * Zs2);
    float nas = (na == 0.f) ? 1.f : na;
    float nss = (ns == 0.f) ? 1.f : ns;
    float Z0, Z1, Z2;
    if (na > ns) { Z0 = Za0 / nas; Z1 = Za1 / nas; Z2 = Za2 / nas; }
    else         { Z0 = Zs0 / nss; Z1 = Zs1 / nss; Z2 = Zs2 / nss; }
    float Y0 = Z1 * X2 - Z2 * X1;
    float Y1 = Z2 * X0 - Z0 * X2;
    float Y2 = Z0 * X1 - Z1 * X0;
    bool nanbad = (Y0 != Y0) || (Y1 != Y1) || (Y2 != Y2);
    float C0 = X1 * Y2 - X2 * Y1;
    float C1 = X2 * Y0 - X0 * Y2;
    float C2 = X0 * Y1 - X1 * Y0;
    float dotv = C0 * Z0 + C1 * Z1 + C2 * Z2;
    if (dotv < 0.f) { Y0 = -Y0; Y1 = -Y1; Y2 = -Y2; }
    bool bad = close || (nd == 0.f) || (na == 0.f) || (ns == 0.f) || nanbad;
    if (bad) {
#pragma unroll
        for (int k = 0; k < 9; k++) R[k] = RA[k];
#pragma unroll
        for (int k = 0; k < 3; k++) O[k] = OA[k];
    } else {
        R[0] = X0; R[1] = X1; R[2] = X2;
        R[3] = Y0; R[4] = Y1; R[5] = Y2;
        R[6] = Z0; R[7] = Z1; R[8] = Z2;
        O[0] = 0.5f * (OA[0] + OB[0]);
        O[1] = 0.5f * (OA[1] + OB[1]);
        O[2] = 0.5f * (OA[2] + OB[2]);
    }
}

// Fused fill+merge: wave-per-row; exclusive prefix recomputed from rowcnt
// (L2-resident). For each found pair, merge pred+target base frames and write
// the fused 24-float record directly. Block 0 wave 0 writes total count.
__global__ void k_fillmerge(const int* __restrict__ m, int L,
                            const unsigned int* __restrict__ rowcnt,
                            unsigned int* __restrict__ count, int cap,
                            const float* __restrict__ pF, const float* __restrict__ tF,
                            float* __restrict__ rec) {
    int i = blockIdx.x * 4 + (threadIdx.x >> 6);
    int lane = threadIdx.x & 63;

    if (blockIdx.x == 0 && (threadIdx.x >> 6) == 0) {
        unsigned int t = 0;
        for (int r = lane; r < L; r += 64) t += rowcnt[r];
#pragma unroll
        for (int off = 1; off < 64; off <<= 1) t += __shfl_xor(t, off, 64);
        if (lane == 0) *count = t;
    }
    if (i >= L) return;

    unsigned int p = 0;
    for (int r = lane; r < i; r += 64) p += rowcnt[r];
#pragma unroll
    for (int off = 1; off < 64; off <<= 1) p += __shfl_xor(p, off, 64);
    unsigned int base = p;

    const int* row = m + (size_t)i * L;
    unsigned long long lt = (lane == 0) ? 0ull : ((1ull << lane) - 1ull);
    for (int j0 = 0; j0 < L; j0 += 64) {
        int j = j0 + lane;
        bool v = (j < L) && (j > i) && (row[j] == 1);
        unsigned long long b = __ballot(v);
        if (v) {
            unsigned int pos = base + (unsigned int)__popcll(b & lt);
            if (pos < (unsigned int)cap) {
                float Rp[9], Op[3], Rt[9], Ot[3];
                merge_frames(pF + i * 12, pF + j * 12, Rp, Op);
                merge_frames(tF + i * 12, tF + j * 12, Rt, Ot);
                write_rec(rec + (size_t)(L + pos) * 24, Rp, Op, Rt, Ot);
            }
        }
        base += (unsigned int)__popcll(b);
    }
}

// Frame-major: each thread owns ONE frame; its 21 constants are PINNED into
// VGPRs (inline-asm) so the allocator cannot rematerialize/reload them per
// iteration (R4/R7 evidence: without pinning the compiler picks 32 VGPRs and
// re-reads the record from global inside the loop). Points staged in LDS as
// padded float4 (wave-uniform broadcast reads, conflict-free).
__global__ __launch_bounds__(256, 4)
void k_main(const float* __restrict__ coor, const float* __restrict__ target,
            const float* __restrict__ rec, const unsigned int* __restrict__ count,
            int cap, int L, int Npts, double* __restrict__ partials) {
    __shared__ float4 sC[CHUNK];
    __shared__ float4 sT[CHUNK];
    __shared__ float sRed[4];
    unsigned int cnt = *count;
    if (cnt > (unsigned int)cap) cnt = (unsigned int)cap;
    int F = L + (int)cnt;
    int nfb = (F + 255) >> 8;
    int nyc = (Npts + CHUNK - 1) / CHUNK;
    int total = nfb * nyc;
    float a0 = 0.f, a1 = 0.f;

    for (int chunk = blockIdx.x; chunk < total; chunk += gridDim.x) {
        int fb = chunk % nfb;
        int yc = chunk / nfb;
        int n0 = yc * CHUNK;
        int npts = Npts - n0; if (npts > CHUNK) npts = CHUNK;
        __syncthreads();   // protect LDS reuse across grid-stride iterations
        for (int idx = threadIdx.x; idx < npts; idx += 256) {
            int g = (n0 + idx) * 3;
            sC[idx] = make_float4(coor[g], coor[g + 1], coor[g + 2], 0.f);
            sT[idx] = make_float4(target[g], target[g + 1], target[g + 2], 0.f);
        }
        __syncthreads();
        int f = fb * 256 + threadIdx.x;
        if (f >= F) continue;   // both barriers above executed by all threads

        const float4* fr = (const float4*)(rec + (size_t)f * 24);
        float4 r0 = fr[0], r1 = fr[1], r2 = fr[2], r3 = fr[3], r4 = fr[4], r5 = fr[5];
        float P00 = r0.x, P01 = r0.y, P02 = r0.z;
        float P10 = r0.w, P11 = r1.x, P12 = r1.y;
        float P20 = r1.z, P21 = r1.w, P22 = r2.x;
        float N00 = r2.y, N01 = r2.z, N02 = r2.w;
        float N10 = r3.x, N11 = r3.y, N12 = r3.z;
        float N20 = r3.w, N21 = r4.x, N22 = r4.y;
        float kx  = r4.z, ky  = r4.w, kz  = r5.x;
        // pin all 21 constants into VGPRs for the whole inner loop
        PIN(P00); PIN(P01); PIN(P02); PIN(P10); PIN(P11); PIN(P12);
        PIN(P20); PIN(P21); PIN(P22);
        PIN(N00); PIN(N01); PIN(N02); PIN(N10); PIN(N11); PIN(N12);
        PIN(N20); PIN(N21); PIN(N22);
        PIN(kx);  PIN(ky);  PIN(kz);

#pragma unroll 4
        for (int n = 0; n < npts; n++) {
            float4 c = sC[n];
            float4 t = sT[n];
            float ux = kx + P00 * c.x + P01 * c.y + P02 * c.z
                          + N00 * t.x + N01 * t.y + N02 * t.z;
            float uy = ky + P10 * c.x + P11 * c.y + P12 * c.z
                          + N10 * t.x + N11 * t.y + N12 * t.z;
            float uz = kz + P20 * c.x + P21 * c.y + P22 * c.z
                          + N20 * t.x + N21 * t.y + N22 * t.z;
            float s = ux * ux + uy * uy + uz * uz + 3.0f * EPV;
            float r = fminf(__builtin_amdgcn_sqrtf(s), EPMAXV);
            if (n & 1) a1 += r; else a0 += r;
        }
    }

    float a = a0 + a1;
#pragma unroll
    for (int off = 32; off > 0; off >>= 1) a += __shfl_down(a, off, 64);
    int lane = threadIdx.x & 63, wv = threadIdx.x >> 6;
    if (lane == 0) sRed[wv] = a;
    __syncthreads();
    if (threadIdx.x == 0)
        partials[blockIdx.x] = (double)(sRed[0] + sRed[1] + sRed[2] + sRed[3]);
}

__global__ void k_final(const double* __restrict__ partials, int npart,
                        const unsigned int* __restrict__ count, int cap,
                        int L, int Npts, float* __restrict__ out) {
    __shared__ double sR[4];
    double d = 0.0;
    for (int i = threadIdx.x; i < npart; i += 256) d += partials[i];
#pragma unroll
    for (int off = 32; off > 0; off >>= 1) d += __shfl_down(d, off, 64);
    int lane = threadIdx.x & 63, wv = threadIdx.x >> 6;
    if (lane == 0) sR[wv] = d;
    __syncthreads();
    if (threadIdx.x == 0) {
        double tot = sR[0] + sR[1] + sR[2] + sR[3];
        unsigned int cnt = *count;
        if (cnt > (unsigned int)cap) cnt = (unsigned int)cap;
        double F = (double)(L + (int)cnt);
        out[0] = (float)(tot / ((double)Npts * F));
    }
}

extern "C" void kernel_launch(void* const* d_in, const int* in_sizes, int n_in,
                              void* d_out, int out_size, void* d_ws, size_t ws_size,
                              hipStream_t stream) {
    const float* coor   = (const float*)d_in[0];
    const float* rot    = (const float*)d_in[1];
    const float* trans  = (const float*)d_in[2];
    const float* target = (const float*)d_in[3];
    const int*   matrix = (const int*)d_in[4];
    int L    = in_sizes[2] / 3;     // trans has L*3 elements
    int Npts = 3 * L;

    char* ws = (char*)d_ws;
    size_t off = 16;
    unsigned int* count  = (unsigned int*)ws;
    unsigned int* rowcnt = (unsigned int*)(ws + off); off += 4 * (size_t)L;
    off = (off + 15) & ~(size_t)15;
    double* partials = (double*)(ws + off); off += 8 * (size_t)NPART;
    off = (off + 15) & ~(size_t)15;
    float* pF = (float*)(ws + off); off += 48 * (size_t)L;   // L*12 floats
    float* tF = (float*)(ws + off); off += 48 * (size_t)L;
    off = (off + 15) & ~(size_t)15;
    // remaining need(cap) = 96*(L+cap)  (rec records, 96 B each)
    long cap_ws = ((long)ws_size - (long)off - 96L * (long)L) / 96;
    long capl = cap_ws < 32768 ? cap_ws : 32768;
    if (capl < 0) capl = 0;
    int cap = (int)capl;
    float* rec = (float*)(ws + off);

    int nrb   = (L + 3) / 4;       // wave-per-row blocks
    int nbase = (L + 255) / 256;
    k_prep<<<nrb + nbase, 256, 0, stream>>>(matrix, L, rowcnt, rot, trans, target,
                                            nrb, pF, tF, rec);
    k_fillmerge<<<nrb, 256, 0, stream>>>(matrix, L, rowcnt, count, cap, pF, tF, rec);
    k_main<<<NPART, 256, 0, stream>>>(coor, target, rec, count, cap, L, Npts, partials);
    k_final<<<1, 256, 0, stream>>>(partials, NPART, count, cap, L, Npts, (float*)d_out);
}